// Round 1
// baseline (221.245 us; speedup 1.0000x reference)
//
#include <hip/hip_runtime.h>
#include <stdint.h>

// ---- problem constants ----
constexpr int Mdim = 8192;
constexpr int Ndim = 4096;
constexpr int Kdim = 4096;

#define ISF        ((float)(2.0 / 255.0))          // IN_SCALE as f32 (matches jax weak-type demotion)
#define OUT_SCALE  ((float)(2.0 / 255.0 * 0.01))   // IN_SCALE * W_SCALE (double product, then f32)
#define BSCALE     0.01f
// IN_ZP = int(round(1.0/(2/255 + 1e-12))) = 127  (the +1e-12 pulls 127.5 below .5 boundary!)
// x_shifted = x_q - 127 in [-127, 128] -> does NOT fit int8.
// We compute u = x_q - 128 in [-128,127] and correct: acc = GEMM(u,w) + rowsum_w[n].

typedef int i32x4 __attribute__((ext_vector_type(4)));

// ---------------- pre-pass 1: quantize x_float -> int8 (u = clip(round(x/s+127),0,255)-128)
__global__ __launch_bounds__(256) void quantize_x(const float* __restrict__ x,
                                                  int* __restrict__ x8,
                                                  int ngroups) {
  int idx = blockIdx.x * 256 + threadIdx.x;
  int stride = gridDim.x * 256;
  for (int g = idx; g < ngroups; g += stride) {
    float4 v = reinterpret_cast<const float4*>(x)[g];
    int a0 = (int)rintf(v.x / ISF + 127.0f);
    int a1 = (int)rintf(v.y / ISF + 127.0f);
    int a2 = (int)rintf(v.z / ISF + 127.0f);
    int a3 = (int)rintf(v.w / ISF + 127.0f);
    a0 = a0 < 0 ? 0 : (a0 > 255 ? 255 : a0); a0 -= 128;
    a1 = a1 < 0 ? 0 : (a1 > 255 ? 255 : a1); a1 -= 128;
    a2 = a2 < 0 ? 0 : (a2 > 255 ? 255 : a2); a2 -= 128;
    a3 = a3 < 0 ? 0 : (a3 > 255 ? 255 : a3); a3 -= 128;
    x8[g] = (a0 & 0xff) | ((a1 & 0xff) << 8) | ((a2 & 0xff) << 16) |
            (int)(((unsigned)(a3 & 0xff)) << 24);
  }
}

// ---------------- pre-pass 2: w_q int32 -> int8 packed, fused with per-row sum
__global__ __launch_bounds__(256) void convert_w(const int* __restrict__ wq,
                                                 int* __restrict__ w8,
                                                 int* __restrict__ wsum) {
  int row = blockIdx.x;  // 4096 blocks, one per output feature
  const int4* src = reinterpret_cast<const int4*>(wq + (size_t)row * Kdim);
  int* dst = w8 + (size_t)row * (Kdim / 4);
  int s = 0;
#pragma unroll
  for (int i = 0; i < 4; ++i) {
    int idx = i * 256 + threadIdx.x;
    int4 v = src[idx];
    s += v.x + v.y + v.z + v.w;
    dst[idx] = (v.x & 0xff) | ((v.y & 0xff) << 8) | ((v.z & 0xff) << 16) |
               (int)(((unsigned)(v.w & 0xff)) << 24);
  }
  __shared__ int red[256];
  red[threadIdx.x] = s;
  __syncthreads();
  for (int off = 128; off; off >>= 1) {
    if ((int)threadIdx.x < off) red[threadIdx.x] += red[threadIdx.x + off];
    __syncthreads();
  }
  if (threadIdx.x == 0) wsum[row] = red[0];
}

// ---------------- main int8 MFMA GEMM: out[m][n] = (acc + wsum[n]) * OUT_SCALE + bq[n]*0.01
// 128x128 tile, BK=128, 256 threads (4 waves 2x2), global_load_lds(16B) staging,
// XOR swizzle (slot ^= row&7) applied on the *global source* (linear LDS dest, rule #21).
__global__ __launch_bounds__(256) void gemm_i8(const int8_t* __restrict__ A8,
                                               const int8_t* __restrict__ B8,
                                               const int* __restrict__ wsum,
                                               const int* __restrict__ bq,
                                               float* __restrict__ out) {
  __shared__ uint8_t lds[32768];  // A tile [128][128] i8 @0, B tile @16384

  // bijective XCD swizzle: nwg = 2048, divisible by 8
  int bid = blockIdx.x;
  int wg = (bid & 7) * 256 + (bid >> 3);
  int bm = wg >> 5;   // 64 row-tiles
  int bn = wg & 31;   // 32 col-tiles

  const int tid = threadIdx.x;
  const int lane = tid & 63;
  const int wv = tid >> 6;
  const int l15 = lane & 15, hi = lane >> 4;
  const int wr = wv >> 1, wc = wv & 1;
  const int sw = l15 & 7;

  // staging: e = it*256+tid covers 16B unit e of the 16KB tile; r=e>>3, s=e&7
  size_t aSrc[4], bSrc[4];
  int ldsOff[4];
#pragma unroll
  for (int it = 0; it < 4; ++it) {
    int e = it * 256 + tid;
    int r = e >> 3, s = e & 7;
    int col = (s ^ (r & 7)) << 4;  // pre-swizzled global column
    aSrc[it] = (size_t)(bm * 128 + r) * Kdim + col;
    bSrc[it] = (size_t)(bn * 128 + r) * Kdim + col;
    ldsOff[it] = it * 4096 + wv * 1024;  // wave-uniform LDS base
  }

  // fragment row bases (byte offsets into lds)
  int aRow[4], bRow[4];
#pragma unroll
  for (int i = 0; i < 4; ++i) {
    aRow[i] = (wr * 64 + i * 16 + l15) * 128;
    bRow[i] = 16384 + (wc * 64 + i * 16 + l15) * 128;
  }

  i32x4 acc[4][4] = {};

  for (int kt = 0; kt < Kdim / 128; ++kt) {
#pragma unroll
    for (int it = 0; it < 4; ++it)
      __builtin_amdgcn_global_load_lds(
          (const __attribute__((address_space(1))) void*)(A8 + aSrc[it] + (size_t)kt * 128),
          (__attribute__((address_space(3))) void*)(&lds[ldsOff[it]]), 16, 0, 0);
#pragma unroll
    for (int it = 0; it < 4; ++it)
      __builtin_amdgcn_global_load_lds(
          (const __attribute__((address_space(1))) void*)(B8 + bSrc[it] + (size_t)kt * 128),
          (__attribute__((address_space(3))) void*)(&lds[16384 + ldsOff[it]]), 16, 0, 0);
    __syncthreads();  // drains vmcnt

#pragma unroll
    for (int ks = 0; ks < 2; ++ks) {
      i32x4 a[4], b[4];
#pragma unroll
      for (int i = 0; i < 4; ++i)
        a[i] = *reinterpret_cast<const i32x4*>(&lds[aRow[i] + ((((ks << 2) + hi) ^ sw) << 4)]);
#pragma unroll
      for (int j = 0; j < 4; ++j)
        b[j] = *reinterpret_cast<const i32x4*>(&lds[bRow[j] + ((((ks << 2) + hi) ^ sw) << 4)]);
#pragma unroll
      for (int i = 0; i < 4; ++i)
#pragma unroll
        for (int j = 0; j < 4; ++j)
          acc[i][j] = __builtin_amdgcn_mfma_i32_16x16x64_i8(a[i], b[j], acc[i][j], 0, 0, 0);
    }
    __syncthreads();
  }

  // epilogue: C/D layout col = lane&15, row = (lane>>4)*4 + reg
  float fb[4];
  int ws4[4];
#pragma unroll
  for (int j = 0; j < 4; ++j) {
    int c = bn * 128 + wc * 64 + j * 16 + l15;
    fb[j] = (float)bq[c] * BSCALE;
    ws4[j] = wsum[c];
  }
#pragma unroll
  for (int i = 0; i < 4; ++i) {
    int rbase = bm * 128 + wr * 64 + i * 16 + hi * 4;
#pragma unroll
    for (int p = 0; p < 4; ++p) {
      size_t ro = (size_t)(rbase + p) * Ndim + bn * 128 + wc * 64;
#pragma unroll
      for (int j = 0; j < 4; ++j)
        out[ro + j * 16 + l15] = (float)(acc[i][j][p] + ws4[j]) * OUT_SCALE + fb[j];
    }
  }
}

// ---------------- naive fallback (only if ws_size is unexpectedly small)
__global__ void fallback_kernel(const float* __restrict__ x, const int* __restrict__ wq,
                                const int* __restrict__ bq, float* __restrict__ out) {
  int col = blockIdx.x * 16 + (threadIdx.x & 15);
  int row = blockIdx.y * 16 + (threadIdx.x >> 4);
  const float* xr = x + (size_t)row * Kdim;
  const int* wr_ = wq + (size_t)col * Kdim;
  int acc = 0;
  for (int k = 0; k < Kdim; ++k) {
    int v = (int)rintf(xr[k] / ISF + 127.0f);
    v = v < 0 ? 0 : (v > 255 ? 255 : v);
    acc += (v - 127) * wr_[k];
  }
  out[(size_t)row * Ndim + col] = (float)acc * OUT_SCALE + (float)bq[col] * BSCALE;
}

extern "C" void kernel_launch(void* const* d_in, const int* in_sizes, int n_in,
                              void* d_out, int out_size, void* d_ws, size_t ws_size,
                              hipStream_t stream) {
  const float* x = (const float*)d_in[0];
  const int* wq = (const int*)d_in[1];
  const int* bq = (const int*)d_in[2];
  float* out = (float*)d_out;

  const size_t x8_bytes = (size_t)Mdim * Kdim;       // 32 MiB
  const size_t w8_bytes = (size_t)Ndim * Kdim;       // 16 MiB
  const size_t ws_need = x8_bytes + w8_bytes + (size_t)Ndim * sizeof(int);

  if (ws_size >= ws_need) {
    int8_t* x8 = (int8_t*)d_ws;
    int8_t* w8 = x8 + x8_bytes;
    int* wsum = (int*)(w8 + w8_bytes);

    quantize_x<<<2048, 256, 0, stream>>>(x, (int*)x8, Mdim * Kdim / 4);
    convert_w<<<Ndim, 256, 0, stream>>>(wq, (int*)w8, wsum);
    gemm_i8<<<(Mdim / 128) * (Ndim / 128), 256, 0, stream>>>(x8, w8, wsum, bq, out);
  } else {
    dim3 grid(Ndim / 16, Mdim / 16);
    fallback_kernel<<<grid, 256, 0, stream>>>(x, wq, bq, out);
  }
}

// Round 2
// 179.234 us; speedup vs baseline: 1.2344x; 1.2344x over previous
//
#include <hip/hip_runtime.h>
#include <stdint.h>

// ---- problem constants ----
constexpr int Mdim = 8192;
constexpr int Ndim = 4096;
constexpr int Kdim = 4096;
constexpr int NT = Kdim / 128;  // 32 K-tiles of BK=128

#define ISF        ((float)(2.0 / 255.0))          // IN_SCALE
#define OUT_SCALE  ((float)(2.0 / 255.0 * 0.01))   // IN_SCALE * W_SCALE
#define BSCALE     0.01f
// IN_ZP = 127 (the +1e-12 pulls 127.5 below the .5 boundary). x_shifted in [-127,128]
// doesn't fit int8 -> compute u = x_q - 128 in [-128,127]; acc = GEMM(u,w) + rowsum_w[n].

typedef int i32x4 __attribute__((ext_vector_type(4)));

// ---------------- pre-pass 1: quantize x_float -> int8 (u = clip(round(x/s+127),0,255)-128)
__global__ __launch_bounds__(256) void quantize_x(const float* __restrict__ x,
                                                  int* __restrict__ x8,
                                                  int ngroups) {
  int idx = blockIdx.x * 256 + threadIdx.x;
  int stride = gridDim.x * 256;
  for (int g = idx; g < ngroups; g += stride) {
    float4 v = reinterpret_cast<const float4*>(x)[g];
    int a0 = (int)rintf(v.x / ISF + 127.0f);
    int a1 = (int)rintf(v.y / ISF + 127.0f);
    int a2 = (int)rintf(v.z / ISF + 127.0f);
    int a3 = (int)rintf(v.w / ISF + 127.0f);
    a0 = a0 < 0 ? 0 : (a0 > 255 ? 255 : a0); a0 -= 128;
    a1 = a1 < 0 ? 0 : (a1 > 255 ? 255 : a1); a1 -= 128;
    a2 = a2 < 0 ? 0 : (a2 > 255 ? 255 : a2); a2 -= 128;
    a3 = a3 < 0 ? 0 : (a3 > 255 ? 255 : a3); a3 -= 128;
    x8[g] = (a0 & 0xff) | ((a1 & 0xff) << 8) | ((a2 & 0xff) << 16) |
            (int)(((unsigned)(a3 & 0xff)) << 24);
  }
}

// ---------------- pre-pass 2: w_q int32 -> int8 packed, fused per-row sum
__global__ __launch_bounds__(256) void convert_w(const int* __restrict__ wq,
                                                 int* __restrict__ w8,
                                                 int* __restrict__ wsum) {
  int row = blockIdx.x;
  const int4* src = reinterpret_cast<const int4*>(wq + (size_t)row * Kdim);
  int* dst = w8 + (size_t)row * (Kdim / 4);
  int s = 0;
#pragma unroll
  for (int i = 0; i < 4; ++i) {
    int idx = i * 256 + threadIdx.x;
    int4 v = src[idx];
    s += v.x + v.y + v.z + v.w;
    dst[idx] = (v.x & 0xff) | ((v.y & 0xff) << 8) | ((v.z & 0xff) << 16) |
               (int)(((unsigned)(v.w & 0xff)) << 24);
  }
  __shared__ int red[256];
  red[threadIdx.x] = s;
  __syncthreads();
  for (int off = 128; off; off >>= 1) {
    if ((int)threadIdx.x < off) red[threadIdx.x] += red[threadIdx.x + off];
    __syncthreads();
  }
  if (threadIdx.x == 0) wsum[row] = red[0];
}

// ---------------- 256x256 8-phase i8 MFMA GEMM (T2 swizzle + T3/T4 counted vmcnt + T5 setprio)
// LDS: A buf0 @0, A buf1 @32768, B buf0 @65536, B buf1 @98304  (128 KiB total)
#define AS1C const __attribute__((address_space(1))) void*
#define AS3  __attribute__((address_space(3))) void*
#define GLL(src, dst) __builtin_amdgcn_global_load_lds((AS1C)(src), (AS3)(dst), 16, 0, 0)
#define BAR() asm volatile("s_barrier" ::: "memory")
#define MFMA(a, b, c) __builtin_amdgcn_mfma_i32_16x16x64_i8(a, b, c, 0, 0, 0)

__global__ __launch_bounds__(512) void gemm_i8_8ph(const int8_t* __restrict__ A8,
                                                   const int8_t* __restrict__ B8,
                                                   const int* __restrict__ wsum,
                                                   const int* __restrict__ bq,
                                                   float* __restrict__ out) {
  __shared__ uint8_t lds[131072];

  // bijective XCD swizzle: 512 blocks, 512 % 8 == 0
  int bid = blockIdx.x;
  int wg = (bid & 7) * 64 + (bid >> 3);
  int bm = wg >> 4;  // 32 row-tiles
  int bn = wg & 15;  // 16 col-tiles

  const int tid = threadIdx.x;
  const int lane = tid & 63;
  const int wv = tid >> 6;        // 0..7
  const int wr = wv >> 2;         // 0..1 : row-half of C
  const int wc = wv & 3;          // 0..3 : col-quarter of C
  const int l15 = lane & 15, hi = lane >> 4;

  // staging source (per lane): row-chunk r3 of 8, slot s3, pre-swizzled col (rule #21)
  const int r3 = lane >> 3, s3 = lane & 7;
  const int swcol = (s3 ^ r3) << 4;
  const size_t aoff = (size_t)(bm * 256 + wv * 8 + r3) * Kdim + swcol;
  const size_t boff = (size_t)(bn * 256 + wv * 8 + r3) * Kdim + swcol;
  const int ldsw = wv * 1024;

#define ISSUE_A(P, t, half) do { \
    GLL(A8 + aoff + (size_t)(t) * 128 + (size_t)((half) * 128) * Kdim, \
        &lds[(P) * 32768 + (half) * 16384 + ldsw]); \
    GLL(A8 + aoff + (size_t)(t) * 128 + (size_t)((half) * 128 + 64) * Kdim, \
        &lds[(P) * 32768 + (half) * 16384 + 8192 + ldsw]); \
  } while (0)
#define ISSUE_B(P, t, half) do { \
    GLL(B8 + boff + (size_t)(t) * 128 + (size_t)((half) * 128) * Kdim, \
        &lds[65536 + (P) * 32768 + (half) * 16384 + ldsw]); \
    GLL(B8 + boff + (size_t)(t) * 128 + (size_t)((half) * 128 + 64) * Kdim, \
        &lds[65536 + (P) * 32768 + (half) * 16384 + 8192 + ldsw]); \
  } while (0)

  // fragment read addressing (swizzled): slot = (ks*4 + hi) ^ (l15&7)
  const int aRow = (wr * 128 + l15) * 128;
  const int bRow = (wc * 64 + l15) * 128;
  const int sl0 = (hi ^ (l15 & 7)) << 4;
  const int sl1 = ((4 + hi) ^ (l15 & 7)) << 4;

#define LDA(P, i, ks) (*reinterpret_cast<const i32x4*>( \
    &lds[(P) * 32768 + aRow + (i) * 2048 + ((ks) ? sl1 : sl0)]))
#define LDB(P, j, ks) (*reinterpret_cast<const i32x4*>( \
    &lds[65536 + (P) * 32768 + bRow + (j) * 2048 + ((ks) ? sl1 : sl0)]))

  i32x4 acc[8][4];
#pragma unroll
  for (int i = 0; i < 8; ++i)
#pragma unroll
    for (int j = 0; j < 4; ++j) acc[i][j] = (i32x4){0, 0, 0, 0};

  // prologue: K0 fully (8 loads) + K1 A-halves (4 loads); keep K1's A in flight
  ISSUE_A(0, 0, 0); ISSUE_A(0, 0, 1);
  ISSUE_B(0, 0, 0); ISSUE_B(0, 0, 1);
  ISSUE_A(1, 1, 0); ISSUE_A(1, 1, 1);
  asm volatile("s_waitcnt vmcnt(4)" ::: "memory");
  BAR();

  // One K-tile = 4 phases. Issue schedule (lifetime-safe):
  //  p1: K[t+1] B-top   p2: K[t+1] B-bot   p3: K[t+2] A-top   p4: K[t+2] A-bot
  //  A-region of buf P last read at p2 -> overwrite issue at p3 OK.
  //  B-region last read at p4 -> overwrite issued next tile p1/p2 OK.
  //  vmcnt(4) at p4 leaves exactly K[t+2]'s 2 A half-tiles (4 loads) in flight.
#define KTILE(P, t, DOB, DOA, VM4, VM0) do { \
    i32x4 a0[8], a1[8], bb0, bb1; \
    /* phase 1 */ \
    if (DOB) ISSUE_B((P) ^ 1, (t) + 1, 0); \
    bb0 = LDB(P, 0, 0); bb1 = LDB(P, 1, 0); \
    _Pragma("unroll") for (int i = 0; i < 8; ++i) a0[i] = LDA(P, i, 0); \
    BAR(); __builtin_amdgcn_s_setprio(1); \
    _Pragma("unroll") for (int i = 0; i < 8; ++i) { \
      acc[i][0] = MFMA(a0[i], bb0, acc[i][0]); acc[i][1] = MFMA(a0[i], bb1, acc[i][1]); } \
    __builtin_amdgcn_s_setprio(0); BAR(); \
    /* phase 2 */ \
    if (DOB) ISSUE_B((P) ^ 1, (t) + 1, 1); \
    bb0 = LDB(P, 2, 0); bb1 = LDB(P, 3, 0); \
    _Pragma("unroll") for (int i = 0; i < 8; ++i) a1[i] = LDA(P, i, 1); \
    BAR(); __builtin_amdgcn_s_setprio(1); \
    _Pragma("unroll") for (int i = 0; i < 8; ++i) { \
      acc[i][2] = MFMA(a0[i], bb0, acc[i][2]); acc[i][3] = MFMA(a0[i], bb1, acc[i][3]); } \
    __builtin_amdgcn_s_setprio(0); BAR(); \
    /* phase 3 */ \
    if (DOA) ISSUE_A(P, (t) + 2, 0); \
    bb0 = LDB(P, 0, 1); bb1 = LDB(P, 1, 1); \
    BAR(); __builtin_amdgcn_s_setprio(1); \
    _Pragma("unroll") for (int i = 0; i < 8; ++i) { \
      acc[i][0] = MFMA(a1[i], bb0, acc[i][0]); acc[i][1] = MFMA(a1[i], bb1, acc[i][1]); } \
    __builtin_amdgcn_s_setprio(0); BAR(); \
    /* phase 4 */ \
    if (DOA) ISSUE_A(P, (t) + 2, 1); \
    bb0 = LDB(P, 2, 1); bb1 = LDB(P, 3, 1); \
    BAR(); __builtin_amdgcn_s_setprio(1); \
    _Pragma("unroll") for (int i = 0; i < 8; ++i) { \
      acc[i][2] = MFMA(a1[i], bb0, acc[i][2]); acc[i][3] = MFMA(a1[i], bb1, acc[i][3]); } \
    __builtin_amdgcn_s_setprio(0); \
    if (VM4) asm volatile("s_waitcnt vmcnt(4)" ::: "memory"); \
    if (VM0) asm volatile("s_waitcnt vmcnt(0)" ::: "memory"); \
    BAR(); \
  } while (0)

  for (int it = 0; it < NT / 2 - 1; ++it) {  // t = 0..29
    int ta = 2 * it, tb = 2 * it + 1;
    KTILE(0, ta, 1, 1, 1, 0);
    KTILE(1, tb, 1, 1, 1, 0);
  }
  // peeled tail: t = 30 (issue K31's B only, drain to 0), t = 31 (pure consume)
  KTILE(0, 30, 1, 0, 0, 1);
  KTILE(1, 31, 0, 0, 0, 0);

  // epilogue: C/D layout col = lane&15, row = (lane>>4)*4 + reg
#pragma unroll
  for (int j = 0; j < 4; ++j) {
    int col = bn * 256 + wc * 64 + j * 16 + l15;
    float fb = (float)bq[col] * BSCALE;
    int ws = wsum[col];
#pragma unroll
    for (int i = 0; i < 8; ++i) {
      int rbase = bm * 256 + wr * 128 + i * 16 + hi * 4;
#pragma unroll
      for (int p = 0; p < 4; ++p)
        out[(size_t)(rbase + p) * Ndim + col] = (float)(acc[i][j][p] + ws) * OUT_SCALE + fb;
    }
  }
#undef KTILE
#undef ISSUE_A
#undef ISSUE_B
#undef LDA
#undef LDB
}

// ---------------- naive fallback (only if ws_size is unexpectedly small)
__global__ void fallback_kernel(const float* __restrict__ x, const int* __restrict__ wq,
                                const int* __restrict__ bq, float* __restrict__ out) {
  int col = blockIdx.x * 16 + (threadIdx.x & 15);
  int row = blockIdx.y * 16 + (threadIdx.x >> 4);
  const float* xr = x + (size_t)row * Kdim;
  const int* wr_ = wq + (size_t)col * Kdim;
  int acc = 0;
  for (int k = 0; k < Kdim; ++k) {
    int v = (int)rintf(xr[k] / ISF + 127.0f);
    v = v < 0 ? 0 : (v > 255 ? 255 : v);
    acc += (v - 127) * wr_[k];
  }
  out[(size_t)row * Ndim + col] = (float)acc * OUT_SCALE + (float)bq[col] * BSCALE;
}

extern "C" void kernel_launch(void* const* d_in, const int* in_sizes, int n_in,
                              void* d_out, int out_size, void* d_ws, size_t ws_size,
                              hipStream_t stream) {
  const float* x = (const float*)d_in[0];
  const int* wq = (const int*)d_in[1];
  const int* bq = (const int*)d_in[2];
  float* out = (float*)d_out;

  const size_t x8_bytes = (size_t)Mdim * Kdim;  // 32 MiB
  const size_t w8_bytes = (size_t)Ndim * Kdim;  // 16 MiB
  const size_t ws_need = x8_bytes + w8_bytes + (size_t)Ndim * sizeof(int);

  if (ws_size >= ws_need) {
    int8_t* x8 = (int8_t*)d_ws;
    int8_t* w8 = x8 + x8_bytes;
    int* wsum = (int*)(w8 + w8_bytes);

    quantize_x<<<2048, 256, 0, stream>>>(x, (int*)x8, Mdim * Kdim / 4);
    convert_w<<<Ndim, 256, 0, stream>>>(wq, (int*)w8, wsum);
    gemm_i8_8ph<<<(Mdim / 256) * (Ndim / 256), 512, 0, stream>>>(x8, w8, wsum, bq, out);
  } else {
    dim3 grid(Ndim / 16, Mdim / 16);
    fallback_kernel<<<grid, 256, 0, stream>>>(x, wq, bq, out);
  }
}